// Round 7
// baseline (125.297 us; speedup 1.0000x reference)
//
#include <hip/hip_runtime.h>
#include <hip/hip_fp16.h>

// SpMM scatter: out[row[e]] += values[e] * x[col[e]],  row sorted, D=64.
// Regime (R5/R6 evidence): gather-LATENCY bound, all pipes <40%. Optimize
// serial memory rounds per wave, not instruction count.
// R7: one node per 64-lane wave; 8 groups x 8 lanes; fp16 rows (128B, h8).
//   round 1: preload col/val for up to 64 edges (2 VMEM, guarded, v=0 pad)
//   round 2: ALL h8 gathers issued back-to-back, count gated by uniform
//            deg-branches (2/4/6/8 loads in flight, no divergence, no loop)
//   then: FMAs, 3-step shfl_xor reduce, 2-instr store. ~2 latency rounds/wave.
// Dispatch 1 (prep): x fp32->fp16 (h8) + row_ptr build, fused (R5-proven).

constexpr int D   = 64;
constexpr int DV  = 16;  // float4 chunks per out row
constexpr int DH8 = 8;   // 16B h8 chunks per fp16 x row (128B)

struct __align__(16) h8 { __half2 a, b, c, d; };

__global__ __launch_bounds__(256) void prep_kernel(
    const int* __restrict__ row,
    const float4* __restrict__ x4,
    h8* __restrict__ xh,
    int* __restrict__ row_ptr,
    int nEdges, int n8, int nNodes)
{
    const int i = blockIdx.x * blockDim.x + threadIdx.x;
    if (i < n8) {                       // fp32 -> fp16, 32B in / 16B out
        const float4 lo = x4[2 * i];
        const float4 hi = x4[2 * i + 1];
        h8 h;
        h.a = __float22half2_rn(make_float2(lo.x, lo.y));
        h.b = __float22half2_rn(make_float2(lo.z, lo.w));
        h.c = __float22half2_rn(make_float2(hi.x, hi.y));
        h.d = __float22half2_rn(make_float2(hi.z, hi.w));
        xh[i] = h;
    }
    if (i < nEdges) {                   // row_ptr build (R2-proven)
        const int r    = row[i];
        const int prev = (i == 0) ? -1 : row[i - 1];
        for (int n = prev + 1; n <= r; ++n) row_ptr[n] = i;
        if (i == nEdges - 1)
            for (int n = r + 1; n <= nNodes; ++n) row_ptr[n] = nEdges;
    }
}

__device__ __forceinline__ void fma_h8(const h8& p, float v, float4& a0, float4& a1)
{
    float2 f;
    f = __half22float2(p.a); a0.x = fmaf(v, f.x, a0.x); a0.y = fmaf(v, f.y, a0.y);
    f = __half22float2(p.b); a0.z = fmaf(v, f.x, a0.z); a0.w = fmaf(v, f.y, a0.w);
    f = __half22float2(p.c); a1.x = fmaf(v, f.x, a1.x); a1.y = fmaf(v, f.y, a1.y);
    f = __half22float2(p.d); a1.z = fmaf(v, f.x, a1.z); a1.w = fmaf(v, f.y, a1.w);
}

__global__ __launch_bounds__(256) void spmm_h8_fan(
    const int* __restrict__ row_ptr,
    const int* __restrict__ col,
    const float* __restrict__ val,
    const h8* __restrict__ xh,
    float4* __restrict__ out4,
    int nNodes)
{
    const int wid = (blockIdx.x * blockDim.x + threadIdx.x) >> 6;   // node id
    if (wid >= nNodes) return;
    const int lane = threadIdx.x & 63;
    const int g    = lane >> 3;     // 0..7 -> edge slot base 2g
    const int sub  = lane & 7;      // 16B h8 chunk within x row

    const int uw    = __builtin_amdgcn_readfirstlane(wid);
    const int start = row_ptr[uw];        // uniform -> s_load
    const int end   = row_ptr[uw + 1];
    const int deg   = end - start;        // wave-uniform

    // round 1: preload up to 64 edges' col/val (2 VMEM). Slots >= deg get
    // cv=0 (safe row), vv=0 (no contribution) -> no per-slot masking later.
    const int  eL  = start + lane;
    const bool okL = eL < end;
    const int   cv = okL ? col[eL] : 0;
    const float vv = okL ? val[eL] : 0.f;

    float4 a0 = {0.f, 0.f, 0.f, 0.f};
    float4 a1 = {0.f, 0.f, 0.f, 0.f};

    // round 2: gather fan-out. Group g owns slots {2g,2g+1, +16, +32, +48}.
    // deg-branches are wave-uniform -> s_cbranch, no divergence. All loads
    // issue before any FMA -> one gather-latency round, 2..8 in flight.
    const bool b1 = deg > 16, b2 = deg > 32, b3 = deg > 48;
    const int s0 = 2 * g;
    const int   c0 = __shfl(cv, s0, 64),     c1 = __shfl(cv, s0 + 1, 64);
    const float v0 = __shfl(vv, s0, 64),     v1 = __shfl(vv, s0 + 1, 64);
    h8 p0, p1, p2, p3, p4, p5, p6, p7;
    int c2=0,c3=0,c4=0,c5=0,c6=0,c7=0;
    float v2=0.f,v3=0.f,v4=0.f,v5=0.f,v6=0.f,v7=0.f;
    p0 = xh[(size_t)c0 * DH8 + sub];
    p1 = xh[(size_t)c1 * DH8 + sub];
    if (b1) {
        c2 = __shfl(cv, s0 + 16, 64); v2 = __shfl(vv, s0 + 16, 64);
        c3 = __shfl(cv, s0 + 17, 64); v3 = __shfl(vv, s0 + 17, 64);
        p2 = xh[(size_t)c2 * DH8 + sub];
        p3 = xh[(size_t)c3 * DH8 + sub];
    }
    if (b2) {
        c4 = __shfl(cv, s0 + 32, 64); v4 = __shfl(vv, s0 + 32, 64);
        c5 = __shfl(cv, s0 + 33, 64); v5 = __shfl(vv, s0 + 33, 64);
        p4 = xh[(size_t)c4 * DH8 + sub];
        p5 = xh[(size_t)c5 * DH8 + sub];
    }
    if (b3) {
        c6 = __shfl(cv, s0 + 48, 64); v6 = __shfl(vv, s0 + 48, 64);
        c7 = __shfl(cv, s0 + 49, 64); v7 = __shfl(vv, s0 + 49, 64);
        p6 = xh[(size_t)c6 * DH8 + sub];
        p7 = xh[(size_t)c7 * DH8 + sub];
    }
    fma_h8(p0, v0, a0, a1);
    fma_h8(p1, v1, a0, a1);
    if (b1) { fma_h8(p2, v2, a0, a1); fma_h8(p3, v3, a0, a1); }
    if (b2) { fma_h8(p4, v4, a0, a1); fma_h8(p5, v5, a0, a1); }
    if (b3) { fma_h8(p6, v6, a0, a1); fma_h8(p7, v7, a0, a1); }

    // rare remainder (deg > 64): direct loads, 8 edges per iteration
    for (int ebase = start + 64; ebase < end; ebase += 16) {
        const int e0 = ebase + 2 * g, e1 = e0 + 1;
        int cc0 = 0, cc1 = 0; float vv0 = 0.f, vv1 = 0.f;
        if (e0 < end) { cc0 = col[e0]; vv0 = val[e0]; }
        if (e1 < end) { cc1 = col[e1]; vv1 = val[e1]; }
        const h8 q0 = xh[(size_t)cc0 * DH8 + sub];
        const h8 q1 = xh[(size_t)cc1 * DH8 + sub];
        fma_h8(q0, vv0, a0, a1);
        fma_h8(q1, vv1, a0, a1);
    }

    // reduce across the 8 groups (lanes ^8, ^16, ^32)
    #pragma unroll
    for (int off = 8; off <= 32; off <<= 1) {
        a0.x += __shfl_xor(a0.x, off, 64); a0.y += __shfl_xor(a0.y, off, 64);
        a0.z += __shfl_xor(a0.z, off, 64); a0.w += __shfl_xor(a0.w, off, 64);
        a1.x += __shfl_xor(a1.x, off, 64); a1.y += __shfl_xor(a1.y, off, 64);
        a1.z += __shfl_xor(a1.z, off, 64); a1.w += __shfl_xor(a1.w, off, 64);
    }
    if (g == 0) {   // lanes 0..7: lane sub owns features [8sub, 8sub+8)
        out4[(size_t)wid * DV + 2 * sub]     = a0;
        out4[(size_t)wid * DV + 2 * sub + 1] = a1;
    }
}

// Fallback (ws too small): single-dispatch p-search kernel, fp32 (R3-proven).
__global__ __launch_bounds__(256) void spmm_psearch(
    const int* __restrict__ row,
    const int* __restrict__ col,
    const float* __restrict__ val,
    const float4* __restrict__ x4,
    float4* __restrict__ out4,
    int nEdges, int nNodes)
{
    const int wid = (blockIdx.x * blockDim.x + threadIdx.x) >> 6;
    if (wid >= nNodes) return;
    const int lane  = threadIdx.x & 63;
    const int group = lane >> 4;
    const int sub   = lane & 15;

    int lo = 0, hi = nEdges;
    const int t0 = wid;
    while (hi > lo) {
        const int span = hi - lo + 1;
        if (span <= 64) {
            const int idx = lo + lane;
            const bool lt = (idx <= hi) && (idx < nEdges) && (row[idx] < t0);
            lo += __popcll(__ballot(lt));
            break;
        }
        const int step = (span + 63) >> 6;
        const int idx  = lo + lane * step;
        const bool lt  = (idx <= hi) && (idx < nEdges) && (row[idx] < t0);
        const int  c   = __popcll(__ballot(lt));
        if (c == 0) { hi = lo; break; }
        const int new_lo = lo + (c - 1) * step + 1;
        if (c < 64) hi = lo + c * step;
        lo = new_lo;
    }
    const int start = lo;
    const int t1 = wid + 1;
    int end = start;
    for (;;) {
        const int idx = end + lane;
        const bool lt = (idx < nEdges) && (row[idx] < t1);
        const int  c  = __popcll(__ballot(lt));
        end += c;
        if (c < 64) break;
    }

    float4 acc = {0.f, 0.f, 0.f, 0.f};
    for (int e = start + group; e < end; e += 8) {
        const int e1 = e + 4;
        const int   c0 = col[e];
        const float v0 = val[e];
        int c1 = c0; float v1 = 0.f;
        if (e1 < end) { c1 = col[e1]; v1 = val[e1]; }
        const float4 x0 = x4[(size_t)c0 * DV + sub];
        const float4 x1 = x4[(size_t)c1 * DV + sub];
        acc.x = fmaf(v0, x0.x, acc.x); acc.y = fmaf(v0, x0.y, acc.y);
        acc.z = fmaf(v0, x0.z, acc.z); acc.w = fmaf(v0, x0.w, acc.w);
        acc.x = fmaf(v1, x1.x, acc.x); acc.y = fmaf(v1, x1.y, acc.y);
        acc.z = fmaf(v1, x1.z, acc.z); acc.w = fmaf(v1, x1.w, acc.w);
    }
    #pragma unroll
    for (int off = 16; off <= 32; off <<= 1) {
        acc.x += __shfl_xor(acc.x, off, 64);
        acc.y += __shfl_xor(acc.y, off, 64);
        acc.z += __shfl_xor(acc.z, off, 64);
        acc.w += __shfl_xor(acc.w, off, 64);
    }
    if (group == 0) out4[(size_t)wid * DV + sub] = acc;
}

extern "C" void kernel_launch(void* const* d_in, const int* in_sizes, int n_in,
                              void* d_out, int out_size, void* d_ws, size_t ws_size,
                              hipStream_t stream)
{
    const int*    row  = (const int*)   d_in[0];
    const int*    col  = (const int*)   d_in[1];
    const float*  val  = (const float*) d_in[2];
    const float4* x4   = (const float4*)d_in[3];
    float4*       out4 = (float4*)d_out;

    const int nEdges = in_sizes[0];
    const int nNodes = out_size / D;            // 100000
    const int n8     = nNodes * DH8;            // 800k h8 chunks

    const dim3 block(256);
    const dim3 gridMain(((size_t)nNodes * 64 + 255) / 256);

    const size_t rp_bytes = (size_t)(nNodes + 1) * sizeof(int);
    const size_t xh_off   = (rp_bytes + 255) & ~(size_t)255;
    const size_t need     = xh_off + (size_t)nNodes * D * sizeof(__half);

    if (ws_size >= need) {
        int* row_ptr = (int*)d_ws;
        h8*  xh      = (h8*)((char*)d_ws + xh_off);
        const int prep_n = (nEdges > n8) ? nEdges : n8;
        prep_kernel<<<dim3((prep_n + 255) / 256), block, 0, stream>>>(
            row, x4, xh, row_ptr, nEdges, n8, nNodes);
        spmm_h8_fan<<<gridMain, block, 0, stream>>>(
            row_ptr, col, val, xh, out4, nNodes);
    } else {
        spmm_psearch<<<gridMain, block, 0, stream>>>(
            row, col, val, x4, out4, nEdges, nNodes);
    }
}